// Round 5
// baseline (2377.501 us; speedup 1.0000x reference)
//
#include <hip/hip_runtime.h>
#include <hip/hip_bf16.h>

#define TLEN 2048
#define BSZ  2048

typedef float f32x4 __attribute__((ext_vector_type(4)));
typedef short bf16x8 __attribute__((ext_vector_type(8)));
typedef unsigned int u32;

__device__ __forceinline__ unsigned short f2b(float f) {
    union { __hip_bfloat16 h; unsigned short u; } v;
    v.h = __float2bfloat16(f);             // HW cvt, RNE (compiler fuses pairs to cvt_pk)
    return v.u;
}

// k-slot permutation: frag slot (g,e) of K-tile kk holds k = sigma_k(kk,g,e).
// Chosen so the D-output registers of the previous (transposed) layer land
// exactly in their own lane's next-layer B-frag slots. Bijective; weights
// (A-side) are loaded with the same sigma, so contraction is k-order safe.
__device__ __forceinline__ constexpr int sigma_k(int kk, int g, int e) {
    return 32*kk + ((e < 4) ? (4*g + e) : (16 + 4*g + (e - 4)));
}

// LeakyReLU(0.1) + pack two f32x4 D-regs into one bf16x8 B-frag
__device__ __forceinline__ bf16x8 leaky_pack(f32x4 lo, f32x4 hi) {
    bf16x8 r;
    #pragma unroll
    for (int i = 0; i < 4; ++i) {
        float x = lo[i]; x = fmaxf(x, 0.1f * x);
        ((unsigned short*)&r)[i] = f2b(x);
        float y = hi[i]; y = fmaxf(y, 0.1f * y);
        ((unsigned short*)&r)[4 + i] = f2b(y);
    }
    return r;
}

__global__ __launch_bounds__(64, 1) void garch_scan_kernel(
    const float* __restrict__ returns, const float* __restrict__ log_rv,
    const float* __restrict__ p_omega, const float* __restrict__ p_beta,
    const float* __restrict__ p_tau1,  const float* __restrict__ p_tau2,
    const float* __restrict__ p_gamma, const float* __restrict__ p_xi,
    const float* __restrict__ p_phi,   const float* __restrict__ p_delta1,
    const float* __restrict__ p_delta2,const float* __restrict__ p_mu,
    const float* __restrict__ W1, const float* __restrict__ b1,
    const float* __restrict__ W2, const float* __restrict__ b2,
    const float* __restrict__ W3, const float* __restrict__ b3,
    const float* __restrict__ W4, const float* __restrict__ b4,
    float* __restrict__ out)
{
    const int lane = threadIdx.x;          // one wave per block
    const int c16  = lane & 15;            // batch row within tile (N dim)
    const int g    = lane >> 4;            // 4-row group (M dim rows 4g+i)
    const bool g0  = (g == 0);

    const float omega = p_omega[0], beta = p_beta[0], tau1 = p_tau1[0],
                tau2 = p_tau2[0],  gma  = p_gamma[0], xi  = p_xi[0],
                phi  = p_phi[0],   d1   = p_delta1[0], d2 = p_delta2[0],
                mu   = p_mu[0];
    const float cb4 = 0.01f * b4[0];

    const int grow = blockIdx.x * 16 + c16;
    const size_t row_off = (size_t)grow * TLEN;
    const float* rp = returns + row_off;
    const float* lp = log_rv  + row_off;

    // ---------------- prologue: weights -> registers (transposed layers) ------
    // A[m=out-col][k] = W[k][m].  b1 folded into W1 at K-slot 5 (feat slot=1.0).
    bf16x8 w1f[8];        // L1: 8 M-tiles, K=32 (k<6 live on g==0)
    bf16x8 w2f[8][4];     // L2: 8 M-tiles x 4 K-tiles (sigma_k)
    bf16x8 w3f[4][4];     // L3: 4 M-tiles x 4 K-tiles (sigma_k)
    bf16x8 w4f[2];        // L4: W4 replicated over m-rows, K=64 (sigma_k)
    f32x4 b2v[8], b3v[4];

    #pragma unroll
    for (int Mt = 0; Mt < 8; ++Mt) {
        const int m = 16*Mt + c16;
        #pragma unroll
        for (int e = 0; e < 8; ++e) {
            float wv = 0.f;
            if (g == 0) { if (e < 5) wv = W1[e*128 + m]; else if (e == 5) wv = b1[m]; }
            ((unsigned short*)&w1f[Mt])[e] = f2b(wv);
        }
        #pragma unroll
        for (int kk = 0; kk < 4; ++kk) {
            #pragma unroll
            for (int e = 0; e < 8; ++e)
                ((unsigned short*)&w2f[Mt][kk])[e] = f2b(W2[sigma_k(kk,g,e)*128 + m]);
        }
        #pragma unroll
        for (int i = 0; i < 4; ++i) b2v[Mt][i] = b2[16*Mt + 4*g + i];
    }
    #pragma unroll
    for (int Mt = 0; Mt < 4; ++Mt) {
        const int m = 16*Mt + c16;
        #pragma unroll
        for (int kk = 0; kk < 4; ++kk) {
            #pragma unroll
            for (int e = 0; e < 8; ++e)
                ((unsigned short*)&w3f[Mt][kk])[e] = f2b(W3[sigma_k(kk,g,e)*64 + m]);
        }
        #pragma unroll
        for (int i = 0; i < 4; ++i) b3v[Mt][i] = b3[16*Mt + 4*g + i];
    }
    #pragma unroll
    for (int kk = 0; kk < 2; ++kk) {
        #pragma unroll
        for (int e = 0; e < 8; ++e)
            ((unsigned short*)&w4f[kk])[e] = f2b(W4[sigma_k(kk,g,e)]);
    }

    // ---------------- decoupled-scan state ----------------
    // lh(t) = lhb(t) + delta(t), delta(t) = beta*c(t-1); everything below the
    // chain head is precomputed in the previous step's MFMA shadow.
    // Invariant at start of iter t: r_n1 = r[t+1], r_n2 = r[t+2]  (clamped).
    const float r0 = rp[0], l0 = lp[0];
    float r_n1 = rp[1], l_n1 = lp[1];
    float r_n2 = rp[2], l_n2 = lp[2];

    float c_prev  = 0.f;                       // c(-1): step 0 has no correction
    float lhb_cur = l0;                        // lh(0) = log_rv[0]
    float lxb_cur = fmaf(phi, lhb_cur, xi);
    float premul  = (r0 - mu) * __expf(-0.5f * lhb_cur);
    float lrv_cur = l0;
    int ti = 0, di = 0;
    unsigned short tod_b = 0, dow_b = 0;       // f2b(0) == 0

    const f32x4 z4 = {0.f, 0.f, 0.f, 0.f};

    #pragma unroll 1
    for (int t = 0; t < TLEN; ++t) {
        // prefetch t+3: becomes r_n2 at end of this iter (r_n1 at iter t+2)
        const int tpf = (t + 3 < TLEN) ? t + 3 : TLEN - 1;
        const float r_ld = rp[tpf];
        const float l_ld = lp[tpf];

        // ---- serial-chain head: only this depends on c(t-1) ----
        const float dlt = beta * c_prev;
        const float q   = fmaf(dlt, fmaf(dlt, 0.125f, -0.5f), 1.0f); // exp(-dlt/2), |err|~d^3/48
        const float zv  = premul * q;
        const float zz  = fmaf(zv, zv, -1.f);
        const float lx  = fmaf(d2, zz, fmaf(d1, zv, fmaf(phi, dlt, lxb_cur)));
        const float uv  = lrv_cur - lx;
        const float lh  = lhb_cur + dlt;

        // ---- feature B-frag (slots: lh,zv,uv,tod,dow,1.0 at k=0..5, g==0) ----
        union { bf16x8 v; u32 d[4]; } fbu;
        fbu.d[0] = g0 ? ((u32)f2b(lh) | ((u32)f2b(zv) << 16)) : 0u;
        fbu.d[1] = g0 ? ((u32)f2b(uv) | ((u32)tod_b  << 16)) : 0u;
        fbu.d[2] = g0 ? ((u32)dow_b  | (0x3F80u << 16))      : 0u;  // 1.0 -> bias slot
        fbu.d[3] = 0u;

        // ---- L1 (bias folded into weights, C=0) ----
        f32x4 acc1[8];
        #pragma unroll
        for (int Mt = 0; Mt < 8; ++Mt)
            acc1[Mt] = __builtin_amdgcn_mfma_f32_16x16x32_bf16(w1f[Mt], fbu.v, z4, 0,0,0);

        // ---- off-chain recurrence for t+1: runs in the MFMA shadow ----
        const float nb   = fmaf(gma, lx, fmaf(tau2, zz, fmaf(tau1, zv, omega)));
        const float lhbn = fmaf(beta, lh, nb);
        const float En   = __expf(-0.5f * lhbn);
        const float lxbn = fmaf(phi, lhbn, xi);
        const float premn= (r_n1 - mu) * En;
        // tod/dow for t+1
        int ti_n = ti + 1, di_n = di;
        if (ti_n == 78) { ti_n = 0; if (++di_n == 5) di_n = 0; }
        const unsigned short tod_n = f2b((float)ti_n * (1.f/77.f));
        const unsigned short dow_n = f2b((float)di_n * 0.25f);

        bf16x8 p1[4];
        #pragma unroll
        for (int kk = 0; kk < 4; ++kk) p1[kk] = leaky_pack(acc1[2*kk], acc1[2*kk+1]);

        // ---- L2: 8 M-tiles, C-chained K accumulation (bias as C-init) ----
        f32x4 acc2[8];
        #pragma unroll
        for (int Mt = 0; Mt < 8; ++Mt) {
            f32x4 a = b2v[Mt];
            #pragma unroll
            for (int kk = 0; kk < 4; ++kk)
                a = __builtin_amdgcn_mfma_f32_16x16x32_bf16(w2f[Mt][kk], p1[kk], a, 0,0,0);
            acc2[Mt] = a;
        }
        bf16x8 p2[4];
        #pragma unroll
        for (int kk = 0; kk < 4; ++kk) p2[kk] = leaky_pack(acc2[2*kk], acc2[2*kk+1]);

        // ---- L3 ----
        f32x4 acc3[4];
        #pragma unroll
        for (int Mt = 0; Mt < 4; ++Mt) {
            f32x4 a = b3v[Mt];
            #pragma unroll
            for (int kk = 0; kk < 4; ++kk)
                a = __builtin_amdgcn_mfma_f32_16x16x32_bf16(w3f[Mt][kk], p2[kk], a, 0,0,0);
            acc3[Mt] = a;
        }
        bf16x8 p3[2];
        #pragma unroll
        for (int kk = 0; kk < 2; ++kk) p3[kk] = leaky_pack(acc3[2*kk], acc3[2*kk+1]);

        // ---- L4: 64->1 dot via K-dim reduction; every D reg = full dot ----
        f32x4 d4 = __builtin_amdgcn_mfma_f32_16x16x32_bf16(w4f[0], p3[0], z4, 0,0,0);
        d4 = __builtin_amdgcn_mfma_f32_16x16x32_bf16(w4f[1], p3[1], d4, 0,0,0);
        const float c_new = fmaf(0.01f, d4[0], cb4);      // c(t) = 0.01*(p + b4)
        const float enh   = lh + c_new;

        // ---- outputs: lane's g picks the stream ----
        const float ov = g0 ? enh : (g == 1) ? lx : (g == 2) ? zv : uv;
        out[(size_t)g * (BSZ * (size_t)TLEN) + row_off + t] = ov;

        // ---- rotate carries ----
        c_prev = c_new; lhb_cur = lhbn; lxb_cur = lxbn; premul = premn;
        lrv_cur = l_n1;
        r_n1 = r_n2; l_n1 = l_n2;
        r_n2 = r_ld; l_n2 = l_ld;
        ti = ti_n; di = di_n; tod_b = tod_n; dow_b = dow_n;
    }
}

extern "C" void kernel_launch(void* const* d_in, const int* in_sizes, int n_in,
                              void* d_out, int out_size, void* d_ws, size_t ws_size,
                              hipStream_t stream) {
    (void)in_sizes; (void)n_in; (void)d_ws; (void)ws_size; (void)out_size;
    const float* returns = (const float*)d_in[0];
    const float* log_rv  = (const float*)d_in[1];
    const float* p_omega = (const float*)d_in[2];
    const float* p_beta  = (const float*)d_in[3];
    const float* p_tau1  = (const float*)d_in[4];
    const float* p_tau2  = (const float*)d_in[5];
    const float* p_gamma = (const float*)d_in[6];
    const float* p_xi    = (const float*)d_in[7];
    const float* p_phi   = (const float*)d_in[8];
    const float* p_d1    = (const float*)d_in[9];
    const float* p_d2    = (const float*)d_in[10];
    const float* p_mu    = (const float*)d_in[11];
    const float* W1 = (const float*)d_in[12];
    const float* b1 = (const float*)d_in[13];
    const float* W2 = (const float*)d_in[14];
    const float* b2 = (const float*)d_in[15];
    const float* W3 = (const float*)d_in[16];
    const float* b3 = (const float*)d_in[17];
    const float* W4 = (const float*)d_in[18];
    const float* b4 = (const float*)d_in[19];
    float* out = (float*)d_out;

    garch_scan_kernel<<<dim3(BSZ / 16), dim3(64), 0, stream>>>(
        returns, log_rv, p_omega, p_beta, p_tau1, p_tau2, p_gamma, p_xi,
        p_phi, p_d1, p_d2, p_mu, W1, b1, W2, b2, W3, b3, W4, b4, out);
}

// Round 6
// 1966.778 us; speedup vs baseline: 1.2088x; 1.2088x over previous
//
#include <hip/hip_runtime.h>
#include <hip/hip_bf16.h>

#define TLEN   2048
#define BSZ    2048
#define CHUNK  128     // output steps per chunk
#define WARM   64      // warm-up steps (state error ~0.75^64 ~ 1e-8)
#define NCHUNK (TLEN / CHUNK)

typedef float f32x4 __attribute__((ext_vector_type(4)));
typedef short bf16x8 __attribute__((ext_vector_type(8)));
typedef unsigned int u32;

__device__ __forceinline__ unsigned short f2b(float f) {
    union { __hip_bfloat16 h; unsigned short u; } v;
    v.h = __float2bfloat16(f);             // HW cvt, RNE
    return v.u;
}

// k-slot permutation: frag slot (g,e) of K-tile kk holds k = sigma_k(kk,g,e).
// Chosen so the D-output registers of the previous (transposed) layer land
// exactly in their own lane's next-layer B-frag slots. Bijective; weights
// (A-side) are loaded with the same sigma, so contraction is k-order safe.
__device__ __forceinline__ constexpr int sigma_k(int kk, int g, int e) {
    return 32*kk + ((e < 4) ? (4*g + e) : (16 + 4*g + (e - 4)));
}

// LeakyReLU(0.1) + pack two f32x4 D-regs into one bf16x8 B-frag
__device__ __forceinline__ bf16x8 leaky_pack(f32x4 lo, f32x4 hi) {
    bf16x8 r;
    #pragma unroll
    for (int i = 0; i < 4; ++i) {
        float x = lo[i]; x = fmaxf(x, 0.1f * x);
        ((unsigned short*)&r)[i] = f2b(x);
        float y = hi[i]; y = fmaxf(y, 0.1f * y);
        ((unsigned short*)&r)[4 + i] = f2b(y);
    }
    return r;
}

__global__ __launch_bounds__(64, 2) void garch_scan_kernel(
    const float* __restrict__ returns, const float* __restrict__ log_rv,
    const float* __restrict__ p_omega, const float* __restrict__ p_beta,
    const float* __restrict__ p_tau1,  const float* __restrict__ p_tau2,
    const float* __restrict__ p_gamma, const float* __restrict__ p_xi,
    const float* __restrict__ p_phi,   const float* __restrict__ p_delta1,
    const float* __restrict__ p_delta2,const float* __restrict__ p_mu,
    const float* __restrict__ W1, const float* __restrict__ b1,
    const float* __restrict__ W2, const float* __restrict__ b2,
    const float* __restrict__ W3, const float* __restrict__ b3,
    const float* __restrict__ W4, const float* __restrict__ b4,
    float* __restrict__ out)
{
    const int lane = threadIdx.x;          // one wave per block
    const int c16  = lane & 15;            // batch row within tile (N dim)
    const int g    = lane >> 4;            // 4-row group (M dim rows 4g+i)
    const bool g0  = (g == 0);

    // chunked-overlap scan geometry: this block owns output steps
    // [t0out, t0out+CHUNK), warm-starting WARM steps earlier (chunk 0: cold).
    const int chunk  = blockIdx.y;
    const int t0out  = chunk * CHUNK;
    const int s0     = (chunk == 0) ? 0 : (t0out - WARM);
    const int nsteps = (chunk == 0) ? CHUNK : (CHUNK + WARM);

    const float omega = p_omega[0], beta = p_beta[0], tau1 = p_tau1[0],
                tau2 = p_tau2[0],  gma  = p_gamma[0], xi  = p_xi[0],
                phi  = p_phi[0],   d1   = p_delta1[0], d2 = p_delta2[0],
                mu   = p_mu[0];
    const float cb4 = 0.01f * b4[0];

    const int grow = blockIdx.x * 16 + c16;
    const size_t row_off = (size_t)grow * TLEN;
    const float* rp = returns + row_off;
    const float* lp = log_rv  + row_off;

    // ---------------- prologue: weights -> registers (transposed layers) ------
    // A[m=out-col][k] = W[k][m].  b1 folded into W1 at K-slot 5 (feat slot=1.0).
    bf16x8 w1f[8];        // L1: 8 M-tiles, K=32 (k<6 live on g==0)
    bf16x8 w2f[8][4];     // L2: 8 M-tiles x 4 K-tiles (sigma_k)
    bf16x8 w3f[4][4];     // L3: 4 M-tiles x 4 K-tiles (sigma_k)
    bf16x8 w4f[2];        // L4: W4 replicated over m-rows, K=64 (sigma_k)
    f32x4 b2v[8], b3v[4];

    #pragma unroll
    for (int Mt = 0; Mt < 8; ++Mt) {
        const int m = 16*Mt + c16;
        #pragma unroll
        for (int e = 0; e < 8; ++e) {
            float wv = 0.f;
            if (g == 0) { if (e < 5) wv = W1[e*128 + m]; else if (e == 5) wv = b1[m]; }
            ((unsigned short*)&w1f[Mt])[e] = f2b(wv);
        }
        #pragma unroll
        for (int kk = 0; kk < 4; ++kk) {
            #pragma unroll
            for (int e = 0; e < 8; ++e)
                ((unsigned short*)&w2f[Mt][kk])[e] = f2b(W2[sigma_k(kk,g,e)*128 + m]);
        }
        #pragma unroll
        for (int i = 0; i < 4; ++i) b2v[Mt][i] = b2[16*Mt + 4*g + i];
    }
    #pragma unroll
    for (int Mt = 0; Mt < 4; ++Mt) {
        const int m = 16*Mt + c16;
        #pragma unroll
        for (int kk = 0; kk < 4; ++kk) {
            #pragma unroll
            for (int e = 0; e < 8; ++e)
                ((unsigned short*)&w3f[Mt][kk])[e] = f2b(W3[sigma_k(kk,g,e)*64 + m]);
        }
        #pragma unroll
        for (int i = 0; i < 4; ++i) b3v[Mt][i] = b3[16*Mt + 4*g + i];
    }
    #pragma unroll
    for (int kk = 0; kk < 2; ++kk) {
        #pragma unroll
        for (int e = 0; e < 8; ++e)
            ((unsigned short*)&w4f[kk])[e] = f2b(W4[sigma_k(kk,g,e)]);
    }

    // ---------------- decoupled-scan state (cold-start at s0) ----------------
    // lh(t) = lhb(t) + delta(t), delta(t) = beta*c(t-1); everything below the
    // chain head is precomputed in the previous step's MFMA shadow.
    // Invariant at start of iter t: r_n1 = r[t+1], r_n2 = r[t+2]  (clamped).
    const float r0 = rp[s0], l0 = lp[s0];
    float r_n1 = rp[s0+1], l_n1 = lp[s0+1];
    float r_n2 = rp[s0+2], l_n2 = lp[s0+2];

    float c_prev  = 0.f;                       // no correction at cold start
    float lhb_cur = l0;                        // lh(s0) := log_rv[s0]
    float lxb_cur = fmaf(phi, lhb_cur, xi);
    float premul  = (r0 - mu) * __expf(-0.5f * lhb_cur);
    float lrv_cur = l0;
    int ti = s0 % 78, di = (s0 / 78) % 5;
    unsigned short tod_b = f2b((float)ti * (1.f/77.f));
    unsigned short dow_b = f2b((float)di * 0.25f);

    const f32x4 z4 = {0.f, 0.f, 0.f, 0.f};

    #pragma unroll 1
    for (int s = 0; s < nsteps; ++s) {
        const int t = s0 + s;
        // prefetch t+3: becomes r_n2 at end of this iter (r_n1 at iter t+2)
        const int tpf = (t + 3 < TLEN) ? t + 3 : TLEN - 1;
        const float r_ld = rp[tpf];
        const float l_ld = lp[tpf];

        // ---- serial-chain head: only this depends on c(t-1) ----
        const float dlt = beta * c_prev;
        const float q   = fmaf(dlt, fmaf(dlt, 0.125f, -0.5f), 1.0f); // exp(-dlt/2), |err|~d^3/48
        const float zv  = premul * q;
        const float zz  = fmaf(zv, zv, -1.f);
        const float lx  = fmaf(d2, zz, fmaf(d1, zv, fmaf(phi, dlt, lxb_cur)));
        const float uv  = lrv_cur - lx;
        const float lh  = lhb_cur + dlt;

        // ---- feature B-frag (slots: lh,zv,uv,tod,dow,1.0 at k=0..5, g==0) ----
        union { bf16x8 v; u32 d[4]; } fbu;
        fbu.d[0] = g0 ? ((u32)f2b(lh) | ((u32)f2b(zv) << 16)) : 0u;
        fbu.d[1] = g0 ? ((u32)f2b(uv) | ((u32)tod_b  << 16)) : 0u;
        fbu.d[2] = g0 ? ((u32)dow_b  | (0x3F80u << 16))      : 0u;  // 1.0 -> bias slot
        fbu.d[3] = 0u;

        // ---- L1 (bias folded into weights, C=0) ----
        f32x4 acc1[8];
        #pragma unroll
        for (int Mt = 0; Mt < 8; ++Mt)
            acc1[Mt] = __builtin_amdgcn_mfma_f32_16x16x32_bf16(w1f[Mt], fbu.v, z4, 0,0,0);

        // ---- off-chain recurrence for t+1: runs in the MFMA shadow ----
        const float nb   = fmaf(gma, lx, fmaf(tau2, zz, fmaf(tau1, zv, omega)));
        const float lhbn = fmaf(beta, lh, nb);
        const float En   = __expf(-0.5f * lhbn);
        const float lxbn = fmaf(phi, lhbn, xi);
        const float premn= (r_n1 - mu) * En;
        // tod/dow for t+1
        int ti_n = ti + 1, di_n = di;
        if (ti_n == 78) { ti_n = 0; if (++di_n == 5) di_n = 0; }
        const unsigned short tod_n = f2b((float)ti_n * (1.f/77.f));
        const unsigned short dow_n = f2b((float)di_n * 0.25f);

        bf16x8 p1[4];
        #pragma unroll
        for (int kk = 0; kk < 4; ++kk) p1[kk] = leaky_pack(acc1[2*kk], acc1[2*kk+1]);

        // ---- L2: 8 M-tiles, C-chained K accumulation (bias as C-init) ----
        f32x4 acc2[8];
        #pragma unroll
        for (int Mt = 0; Mt < 8; ++Mt) {
            f32x4 a = b2v[Mt];
            #pragma unroll
            for (int kk = 0; kk < 4; ++kk)
                a = __builtin_amdgcn_mfma_f32_16x16x32_bf16(w2f[Mt][kk], p1[kk], a, 0,0,0);
            acc2[Mt] = a;
        }
        bf16x8 p2[4];
        #pragma unroll
        for (int kk = 0; kk < 4; ++kk) p2[kk] = leaky_pack(acc2[2*kk], acc2[2*kk+1]);

        // ---- L3 ----
        f32x4 acc3[4];
        #pragma unroll
        for (int Mt = 0; Mt < 4; ++Mt) {
            f32x4 a = b3v[Mt];
            #pragma unroll
            for (int kk = 0; kk < 4; ++kk)
                a = __builtin_amdgcn_mfma_f32_16x16x32_bf16(w3f[Mt][kk], p2[kk], a, 0,0,0);
            acc3[Mt] = a;
        }
        bf16x8 p3[2];
        #pragma unroll
        for (int kk = 0; kk < 2; ++kk) p3[kk] = leaky_pack(acc3[2*kk], acc3[2*kk+1]);

        // ---- L4: 64->1 dot via K-dim reduction; every D reg = full dot ----
        f32x4 d4 = __builtin_amdgcn_mfma_f32_16x16x32_bf16(w4f[0], p3[0], z4, 0,0,0);
        d4 = __builtin_amdgcn_mfma_f32_16x16x32_bf16(w4f[1], p3[1], d4, 0,0,0);
        const float c_new = fmaf(0.01f, d4[0], cb4);      // c(t) = 0.01*(p + b4)
        const float enh   = lh + c_new;

        // ---- outputs (skip during warm-up; wave-uniform branch) ----
        if (t >= t0out) {
            const float ov = g0 ? enh : (g == 1) ? lx : (g == 2) ? zv : uv;
            out[(size_t)g * (BSZ * (size_t)TLEN) + row_off + t] = ov;
        }

        // ---- rotate carries ----
        c_prev = c_new; lhb_cur = lhbn; lxb_cur = lxbn; premul = premn;
        lrv_cur = l_n1;
        r_n1 = r_n2; l_n1 = l_n2;
        r_n2 = r_ld; l_n2 = l_ld;
        ti = ti_n; di = di_n; tod_b = tod_n; dow_b = dow_n;
    }
}

extern "C" void kernel_launch(void* const* d_in, const int* in_sizes, int n_in,
                              void* d_out, int out_size, void* d_ws, size_t ws_size,
                              hipStream_t stream) {
    (void)in_sizes; (void)n_in; (void)d_ws; (void)ws_size; (void)out_size;
    const float* returns = (const float*)d_in[0];
    const float* log_rv  = (const float*)d_in[1];
    const float* p_omega = (const float*)d_in[2];
    const float* p_beta  = (const float*)d_in[3];
    const float* p_tau1  = (const float*)d_in[4];
    const float* p_tau2  = (const float*)d_in[5];
    const float* p_gamma = (const float*)d_in[6];
    const float* p_xi    = (const float*)d_in[7];
    const float* p_phi   = (const float*)d_in[8];
    const float* p_d1    = (const float*)d_in[9];
    const float* p_d2    = (const float*)d_in[10];
    const float* p_mu    = (const float*)d_in[11];
    const float* W1 = (const float*)d_in[12];
    const float* b1 = (const float*)d_in[13];
    const float* W2 = (const float*)d_in[14];
    const float* b2 = (const float*)d_in[15];
    const float* W3 = (const float*)d_in[16];
    const float* b3 = (const float*)d_in[17];
    const float* W4 = (const float*)d_in[18];
    const float* b4 = (const float*)d_in[19];
    float* out = (float*)d_out;

    garch_scan_kernel<<<dim3(BSZ / 16, NCHUNK), dim3(64), 0, stream>>>(
        returns, log_rv, p_omega, p_beta, p_tau1, p_tau2, p_gamma, p_xi,
        p_phi, p_d1, p_d2, p_mu, W1, b1, W2, b2, W3, b3, W4, b4, out);
}

// Round 7
// 389.809 us; speedup vs baseline: 6.0991x; 5.0455x over previous
//
#include <hip/hip_runtime.h>
#include <hip/hip_bf16.h>

#define TLEN   2048
#define BSZ    2048
#define CHUNK  128     // output steps per chunk
#define WARM   64      // warm-up steps (state error ~0.75^64 ~ 1e-8)
#define NCHUNK (TLEN / CHUNK)

typedef float f32x4 __attribute__((ext_vector_type(4)));
typedef short bf16x8 __attribute__((ext_vector_type(8)));
typedef unsigned int u32;

__device__ __forceinline__ unsigned short f2b(float f) {
    union { __hip_bfloat16 h; unsigned short u; } v;
    v.h = __float2bfloat16(f);             // HW cvt, RNE
    return v.u;
}

__device__ __forceinline__ float leaky(float x) { return fmaxf(x, 0.1f * x); }

// k-slot permutation: frag slot (g,e) of K-tile kk holds k = sigma_k(kk,g,e).
// Chosen so the D-output registers of the previous (transposed) layer land
// exactly in their own lane's next-layer B-frag slots. Bijective; weights
// (A-side) are loaded with the same sigma, so contraction is k-order safe.
// Identical slot structure for bf16 (8 shorts) and fp8 (8 bytes) K=32 frags.
__device__ __forceinline__ constexpr int sigma_k(int kk, int g, int e) {
    return 32*kk + ((e < 4) ? (4*g + e) : (16 + 4*g + (e - 4)));
}

// LeakyReLU + pack two f32x4 D-regs into one bf16x8 B-frag
__device__ __forceinline__ bf16x8 leaky_pack(f32x4 lo, f32x4 hi) {
    bf16x8 r;
    #pragma unroll
    for (int i = 0; i < 4; ++i) {
        ((unsigned short*)&r)[i]     = f2b(leaky(lo[i]));
        ((unsigned short*)&r)[4 + i] = f2b(leaky(hi[i]));
    }
    return r;
}

// LeakyReLU + pack two f32x4 D-regs into one fp8x8 B-frag (2 VGPRs, as long)
__device__ __forceinline__ long leaky_pack_fp8(f32x4 lo, f32x4 hi) {
    int d0 = __builtin_amdgcn_cvt_pk_fp8_f32(leaky(lo[0]), leaky(lo[1]), 0,  false);
    d0     = __builtin_amdgcn_cvt_pk_fp8_f32(leaky(lo[2]), leaky(lo[3]), d0, true);
    int d1 = __builtin_amdgcn_cvt_pk_fp8_f32(leaky(hi[0]), leaky(hi[1]), 0,  false);
    d1     = __builtin_amdgcn_cvt_pk_fp8_f32(leaky(hi[2]), leaky(hi[3]), d1, true);
    return (long)(((unsigned long long)(u32)d1 << 32) | (u32)d0);
}

// pack 8 (already scaled) f32 weights into one fp8x8 A-frag
__device__ __forceinline__ long pack_fp8_w(const float wv[8]) {
    int d0 = __builtin_amdgcn_cvt_pk_fp8_f32(wv[0], wv[1], 0,  false);
    d0     = __builtin_amdgcn_cvt_pk_fp8_f32(wv[2], wv[3], d0, true);
    int d1 = __builtin_amdgcn_cvt_pk_fp8_f32(wv[4], wv[5], 0,  false);
    d1     = __builtin_amdgcn_cvt_pk_fp8_f32(wv[6], wv[7], d1, true);
    return (long)(((unsigned long long)(u32)d1 << 32) | (u32)d0);
}

__global__ __launch_bounds__(64, 2) void garch_scan_kernel(
    const float* __restrict__ returns, const float* __restrict__ log_rv,
    const float* __restrict__ p_omega, const float* __restrict__ p_beta,
    const float* __restrict__ p_tau1,  const float* __restrict__ p_tau2,
    const float* __restrict__ p_gamma, const float* __restrict__ p_xi,
    const float* __restrict__ p_phi,   const float* __restrict__ p_delta1,
    const float* __restrict__ p_delta2,const float* __restrict__ p_mu,
    const float* __restrict__ W1, const float* __restrict__ b1,
    const float* __restrict__ W2, const float* __restrict__ b2,
    const float* __restrict__ W3, const float* __restrict__ b3,
    const float* __restrict__ W4, const float* __restrict__ b4,
    float* __restrict__ out)
{
    const int lane = threadIdx.x;          // one wave per block
    const int c16  = lane & 15;            // batch row within tile (N dim)
    const int g    = lane >> 4;            // 4-row group (M dim rows 4g+i)
    const bool g0  = (g == 0);

    // chunked-overlap scan: output steps [t0out, t0out+CHUNK), warm-start WARM
    // steps earlier from the reference's own cold-start rule (chunk 0: exact).
    const int chunk  = blockIdx.y;
    const int t0out  = chunk * CHUNK;
    const int s0     = (chunk == 0) ? 0 : (t0out - WARM);
    const int nsteps = (chunk == 0) ? CHUNK : (CHUNK + WARM);

    const float omega = p_omega[0], beta = p_beta[0], tau1 = p_tau1[0],
                tau2 = p_tau2[0],  gma  = p_gamma[0], xi  = p_xi[0],
                phi  = p_phi[0],   d1   = p_delta1[0], d2 = p_delta2[0],
                mu   = p_mu[0];
    const float cb4 = 0.01f * b4[0];

    const int grow = blockIdx.x * 16 + c16;
    const size_t row_off = (size_t)grow * TLEN;
    const float* rp = returns + row_off;
    const float* lp = log_rv  + row_off;

    // ---------------- prologue: weights -> registers ----------------
    // Transposed layers: A[m=out-col][k] = W[k][m].
    // Scale-folding (LeakyReLU is positively homogeneous):
    //   L1: 8*W1, 8*b1  -> acc1 = 8*pre1,  p1 = 8*h1   (fp8 input of L2)
    //   L2: 8*W2, C=64*b2 -> acc2 = 64*pre2, p2 = 64*h2 (fp8 input of L3)
    //   L3: 8*W3, C=512*b3 -> acc3 = 512*pre3, p3 = 512*h3 (bf16 input of L4)
    //   L4: W4 bf16 -> d4 = 512*p;  c = (0.01/512)*d4 + 0.01*b4
    bf16x8 w1f[8];        // L1 bf16: 8 M-tiles, K=32 (k<6 live on g==0)
    long   w2f[8][4];     // L2 fp8:  8 M-tiles x 4 K-tiles (sigma_k)
    long   w3f[4][4];     // L3 fp8:  4 M-tiles x 4 K-tiles (sigma_k)
    bf16x8 w4f[2];        // L4 bf16: W4 replicated over m-rows, K=64 (sigma_k)
    f32x4 b2v[8], b3v[4];

    #pragma unroll
    for (int Mt = 0; Mt < 8; ++Mt) {
        const int m = 16*Mt + c16;
        #pragma unroll
        for (int e = 0; e < 8; ++e) {
            float wv = 0.f;
            if (g == 0) { if (e < 5) wv = 8.f * W1[e*128 + m]; else if (e == 5) wv = 8.f * b1[m]; }
            ((unsigned short*)&w1f[Mt])[e] = f2b(wv);
        }
        #pragma unroll
        for (int kk = 0; kk < 4; ++kk) {
            float wv[8];
            #pragma unroll
            for (int e = 0; e < 8; ++e) wv[e] = 8.f * W2[sigma_k(kk,g,e)*128 + m];
            w2f[Mt][kk] = pack_fp8_w(wv);
        }
        #pragma unroll
        for (int i = 0; i < 4; ++i) b2v[Mt][i] = 64.f * b2[16*Mt + 4*g + i];
    }
    #pragma unroll
    for (int Mt = 0; Mt < 4; ++Mt) {
        const int m = 16*Mt + c16;
        #pragma unroll
        for (int kk = 0; kk < 4; ++kk) {
            float wv[8];
            #pragma unroll
            for (int e = 0; e < 8; ++e) wv[e] = 8.f * W3[sigma_k(kk,g,e)*64 + m];
            w3f[Mt][kk] = pack_fp8_w(wv);
        }
        #pragma unroll
        for (int i = 0; i < 4; ++i) b3v[Mt][i] = 512.f * b3[16*Mt + 4*g + i];
    }
    #pragma unroll
    for (int kk = 0; kk < 2; ++kk) {
        #pragma unroll
        for (int e = 0; e < 8; ++e)
            ((unsigned short*)&w4f[kk])[e] = f2b(W4[sigma_k(kk,g,e)]);
    }

    // ---------------- decoupled-scan state (cold-start at s0) ----------------
    // lh(t) = lhb(t) + delta(t), delta(t) = beta*c(t-1); everything below the
    // chain head is precomputed in the previous step's MFMA shadow.
    // Invariant at start of iter t: r_n1 = r[t+1], r_n2 = r[t+2]  (clamped).
    const float r0 = rp[s0], l0 = lp[s0];
    float r_n1 = rp[s0+1], l_n1 = lp[s0+1];
    float r_n2 = rp[s0+2], l_n2 = lp[s0+2];

    float c_prev  = 0.f;
    float lhb_cur = l0;                        // lh(s0) := log_rv[s0]
    float lxb_cur = fmaf(phi, lhb_cur, xi);
    float premul  = (r0 - mu) * __expf(-0.5f * lhb_cur);
    float lrv_cur = l0;
    int ti = s0 % 78, di = (s0 / 78) % 5;
    unsigned short tod_b = f2b((float)ti * (1.f/77.f));
    unsigned short dow_b = f2b((float)di * 0.25f);

    const f32x4 z4 = {0.f, 0.f, 0.f, 0.f};

    #pragma unroll 1
    for (int s = 0; s < nsteps; ++s) {
        const int t = s0 + s;
        const int tpf = (t + 3 < TLEN) ? t + 3 : TLEN - 1;
        const float r_ld = rp[tpf];
        const float l_ld = lp[tpf];

        // ---- serial-chain head: only this depends on c(t-1) ----
        const float dlt = beta * c_prev;
        const float q   = fmaf(dlt, fmaf(dlt, 0.125f, -0.5f), 1.0f); // exp(-dlt/2)
        const float zv  = premul * q;
        const float zz  = fmaf(zv, zv, -1.f);
        const float lx  = fmaf(d2, zz, fmaf(d1, zv, fmaf(phi, dlt, lxb_cur)));
        const float uv  = lrv_cur - lx;
        const float lh  = lhb_cur + dlt;

        // ---- feature B-frag (slots: lh,zv,uv,tod,dow,1.0 at k=0..5, g==0) ----
        union { bf16x8 v; u32 d[4]; } fbu;
        fbu.d[0] = g0 ? ((u32)f2b(lh) | ((u32)f2b(zv) << 16)) : 0u;
        fbu.d[1] = g0 ? ((u32)f2b(uv) | ((u32)tod_b  << 16)) : 0u;
        fbu.d[2] = g0 ? ((u32)dow_b  | (0x3F80u << 16))      : 0u;  // 1.0 -> bias slot
        fbu.d[3] = 0u;

        // ---- L1 (bf16; 8*W1 with 8*b1 folded, C=0) ----
        f32x4 acc1[8];
        #pragma unroll
        for (int Mt = 0; Mt < 8; ++Mt)
            acc1[Mt] = __builtin_amdgcn_mfma_f32_16x16x32_bf16(w1f[Mt], fbu.v, z4, 0,0,0);

        // ---- off-chain recurrence for t+1: runs in the MFMA shadow ----
        const float nb   = fmaf(gma, lx, fmaf(tau2, zz, fmaf(tau1, zv, omega)));
        const float lhbn = fmaf(beta, lh, nb);
        const float En   = __expf(-0.5f * lhbn);
        const float lxbn = fmaf(phi, lhbn, xi);
        const float premn= (r_n1 - mu) * En;
        int ti_n = ti + 1, di_n = di;
        if (ti_n == 78) { ti_n = 0; if (++di_n == 5) di_n = 0; }
        const unsigned short tod_n = f2b((float)ti_n * (1.f/77.f));
        const unsigned short dow_n = f2b((float)di_n * 0.25f);

        long p1[4];                              // 8*h1 in fp8
        #pragma unroll
        for (int kk = 0; kk < 4; ++kk) p1[kk] = leaky_pack_fp8(acc1[2*kk], acc1[2*kk+1]);

        // ---- L2 (fp8): 8 M-tiles, C-chained K accumulation, C-init 64*b2 ----
        f32x4 acc2[8];
        #pragma unroll
        for (int Mt = 0; Mt < 8; ++Mt) {
            f32x4 a = b2v[Mt];
            #pragma unroll
            for (int kk = 0; kk < 4; ++kk)
                a = __builtin_amdgcn_mfma_f32_16x16x32_fp8_fp8(w2f[Mt][kk], p1[kk], a, 0,0,0);
            acc2[Mt] = a;
        }
        long p2[4];                              // 64*h2 in fp8
        #pragma unroll
        for (int kk = 0; kk < 4; ++kk) p2[kk] = leaky_pack_fp8(acc2[2*kk], acc2[2*kk+1]);

        // ---- L3 (fp8): C-init 512*b3 ----
        f32x4 acc3[4];
        #pragma unroll
        for (int Mt = 0; Mt < 4; ++Mt) {
            f32x4 a = b3v[Mt];
            #pragma unroll
            for (int kk = 0; kk < 4; ++kk)
                a = __builtin_amdgcn_mfma_f32_16x16x32_fp8_fp8(w3f[Mt][kk], p2[kk], a, 0,0,0);
            acc3[Mt] = a;
        }
        bf16x8 p3[2];                            // 512*h3 in bf16
        #pragma unroll
        for (int kk = 0; kk < 2; ++kk) p3[kk] = leaky_pack(acc3[2*kk], acc3[2*kk+1]);

        // ---- L4 (bf16): 64->1 dot via K-dim; every D reg = 512*p ----
        f32x4 d4 = __builtin_amdgcn_mfma_f32_16x16x32_bf16(w4f[0], p3[0], z4, 0,0,0);
        d4 = __builtin_amdgcn_mfma_f32_16x16x32_bf16(w4f[1], p3[1], d4, 0,0,0);
        const float c_new = fmaf(0.01f/512.f, d4[0], cb4);   // c(t) = 0.01*(p + b4)
        const float enh   = lh + c_new;

        // ---- outputs (skip during warm-up; wave-uniform branch) ----
        if (t >= t0out) {
            const float ov = g0 ? enh : (g == 1) ? lx : (g == 2) ? zv : uv;
            out[(size_t)g * (BSZ * (size_t)TLEN) + row_off + t] = ov;
        }

        // ---- rotate carries ----
        c_prev = c_new; lhb_cur = lhbn; lxb_cur = lxbn; premul = premn;
        lrv_cur = l_n1;
        r_n1 = r_n2; l_n1 = l_n2;
        r_n2 = r_ld; l_n2 = l_ld;
        ti = ti_n; di = di_n; tod_b = tod_n; dow_b = dow_n;
    }
}

extern "C" void kernel_launch(void* const* d_in, const int* in_sizes, int n_in,
                              void* d_out, int out_size, void* d_ws, size_t ws_size,
                              hipStream_t stream) {
    (void)in_sizes; (void)n_in; (void)d_ws; (void)ws_size; (void)out_size;
    const float* returns = (const float*)d_in[0];
    const float* log_rv  = (const float*)d_in[1];
    const float* p_omega = (const float*)d_in[2];
    const float* p_beta  = (const float*)d_in[3];
    const float* p_tau1  = (const float*)d_in[4];
    const float* p_tau2  = (const float*)d_in[5];
    const float* p_gamma = (const float*)d_in[6];
    const float* p_xi    = (const float*)d_in[7];
    const float* p_phi   = (const float*)d_in[8];
    const float* p_d1    = (const float*)d_in[9];
    const float* p_d2    = (const float*)d_in[10];
    const float* p_mu    = (const float*)d_in[11];
    const float* W1 = (const float*)d_in[12];
    const float* b1 = (const float*)d_in[13];
    const float* W2 = (const float*)d_in[14];
    const float* b2 = (const float*)d_in[15];
    const float* W3 = (const float*)d_in[16];
    const float* b3 = (const float*)d_in[17];
    const float* W4 = (const float*)d_in[18];
    const float* b4 = (const float*)d_in[19];
    float* out = (float*)d_out;

    garch_scan_kernel<<<dim3(BSZ / 16, NCHUNK), dim3(64), 0, stream>>>(
        returns, log_rv, p_omega, p_beta, p_tau1, p_tau2, p_gamma, p_xi,
        p_phi, p_d1, p_d2, p_mu, W1, b1, W2, b2, W3, b3, W4, b4, out);
}